// Round 14
// baseline (123.573 us; speedup 1.0000x reference)
//
#include <hip/hip_runtime.h>
#include <math.h>

// NGRU via MFMA, R14 = R9 math, m-split waves, x direct-to-registers
// (zero-redundancy), h-only LDS, single barrier domain.
// Only layer 1 of the 2 parallel GRU layers contributes (reference returns
// h_final[-1]); layer 0 is skipped.
//
// Shapes: x (64,48,256,64) f32; Wih/Whh (2,192,64); bih/bhh (2,192).
// rows = B*N = 16384 independent GRU sequences, T=48, H=64.
//
// Structure: 256 blocks x 512 threads (8 waves), 64 rows/block, 1 block/CU.
// Wave wv: mq = wv>>2 selects rows [32mq,32mq+32); nw = wv&3 selects cols
// [16nw,16nw+16). Per wave: 2 m-tiles x 12 MFMA (R9-length phase; R6
// showed short phases regress), all 4 gates register-local.
//
// KEY vs R9: in the m-split, each wave's x A-fragments are exactly its own
// rows -> per-lane DIRECT global loads in fragment layout have zero
// redundancy across waves (R10's failure was 4x redundant loads + a
// 104-reg squeeze that sank the prefetch; waves_per_eu(2,2) gives 256
// VGPRs so the ~160-reg set cannot spill/sink). x never touches LDS:
//  * LDS is h-only [64][HK=72] ping-pong (18 KB), ds_reads halve,
//  * the 12 x-part MFMAs issue from registers right after the barrier,
//    covering the h ds_read latency,
//  * ONE barrier per step, one domain per CU.
// Chain order per accumulator exactly R9 (bias; X.k0; X.k1; H.k0; H.k1)
// -> bit-identical numerics (absmax must stay 0.00390625).

#define TT 48
#define HH 64
#define GG 192
#define NN 256
#define RPB 64          // rows per block
#define NTHREADS 512    // 8 waves
#define HK 72           // h row stride in halfs (64 + 8 pad)
#define HBUF (RPB*HK)   // 4608 halfs per h buffer

typedef _Float16 h8 __attribute__((ext_vector_type(8)));   // 8 fp16 (4 VGPRs)
typedef __attribute__((ext_vector_type(4))) float f32x4;   // MFMA accum
typedef __attribute__((ext_vector_type(4))) unsigned u32x4;

__device__ __forceinline__ float sigm(float v) {
    return __builtin_amdgcn_rcpf(1.f + __expf(-v));
}
__device__ __forceinline__ float tanh_f(float v) {
    float a = fabsf(v);
    float e = __expf(2.f * a);
    float t = 1.f - 2.f * __builtin_amdgcn_rcpf(e + 1.f);
    return v < 0.f ? -t : t;
}
// pack 2 f32 -> dword of 2 fp16 (RNE)
__device__ __forceinline__ unsigned pkh2(float a, float b) {
    union { _Float16 h[2]; unsigned u; } c;
    c.h[0] = (_Float16)a; c.h[1] = (_Float16)b;
    return c.u;
}
// 8 consecutive f32 (two float4) -> one fp16 A-fragment, k-ascending
__device__ __forceinline__ h8 cvt_frag(float4 a, float4 b) {
    u32x4 w = {pkh2(a.x, a.y), pkh2(a.z, a.w),
               pkh2(b.x, b.y), pkh2(b.z, b.w)};
    return __builtin_bit_cast(h8, w);
}

#define MF(A, B, C) __builtin_amdgcn_mfma_f32_16x16x32_f16(A, B, C, 0, 0, 0)

__global__ __launch_bounds__(NTHREADS)
__attribute__((amdgpu_waves_per_eu(2, 2)))
void ngru_mfma14(const float* __restrict__ x,
                 const float* __restrict__ Wih,
                 const float* __restrict__ Whh,
                 const float* __restrict__ bih,
                 const float* __restrict__ bhh,
                 float* __restrict__ out)
{
    extern __shared__ __align__(16) _Float16 lds_h[];  // 2 x HBUF halfs (h only)

    const int tid  = threadIdx.x;
    const int lane = tid & 63;
    const int wv   = tid >> 6;          // wave 0..7
    const int mq   = wv >> 2;           // row group: rows [32mq, 32mq+32)
    const int nw   = wv & 3;            // j slice [16nw, 16nw+16)
    const int c0   = lane & 15;         // C col within tile / A row index
    const int rq   = lane >> 4;         // quarter-wave
    const int j    = nw * 16 + c0;
    const int rbase = mq * 32;

    const int grow0 = blockIdx.x * RPB;
    const int bb    = grow0 / NN;       // 64-row blocks never straddle a batch
    const int n0    = grow0 % NN;

    const float* Wi = Wih + GG * HH;    // layer 1
    const float* Wh = Whh + GG * HH;

    // ---- B fragments (fp16) in registers: 12 kt-slots (R9 layout) ----
    // slot: r -> 0..3 (kt0,1 = Wi over x; kt2,3 = Wh over h); z -> 4..7;
    //       gin -> 8,9 (Wi, x kt0,1); ghn -> 10,11 (Wh, h kt0,1).
    h8 Bf[12];
    #pragma unroll
    for (int g = 0; g < 4; ++g) {
        const int ktlo = (g == 3) ? 2 : 0;
        const int kthi = (g == 2) ? 2 : 4;
        #pragma unroll
        for (int kt = ktlo; kt < kthi; ++kt) {
            const int slot = (g < 2) ? g * 4 + kt : 8 + (g - 2) * 2 + (kt & 1);
            const bool isWi = (kt < 2);
            const int gbase = (g >= 2) ? 2 : g;
            const float* src = (isWi ? Wi : Wh)
                             + (gbase * 64 + j) * HH + (kt & 1) * 32 + rq * 8;
            h8 f;
            #pragma unroll
            for (int q = 0; q < 8; ++q) f[q] = (_Float16)src[q];
            Bf[slot] = f;
        }
    }

    // ---- biases (layer 1), r/z pre-summed; n biases separate ----
    const float brz  = bih[GG + j]      + bhh[GG + j];
    const float bzz  = bih[GG + 64 + j] + bhh[GG + 64 + j];
    const float bin_ = bih[GG + 128 + j];
    const float bhn_ = bhh[GG + 128 + j];

    // ---- zero h buffer 0 ----
    for (int idx = tid; idx < HBUF / 2; idx += NTHREADS)
        *(unsigned*)(lds_h + idx * 2) = 0u;

    // ---- x fragment base: lane (c0,rq) of m-tile m reads its OWN A-frag
    // elements: x[rbase+m*16+c0][kt*32 + rq*8 .. +8)  (2 float4 per frag) ----
    // prologue: x(0) frags
    h8 Xf[2][2];
    {
        const float* xb = x + ((size_t)(bb * TT) * NN + n0) * HH;
        #pragma unroll
        for (int m = 0; m < 2; ++m)
            #pragma unroll
            for (int kt = 0; kt < 2; ++kt) {
                const float* s_ = xb + (rbase + m * 16 + c0) * HH
                                + kt * 32 + rq * 8;
                Xf[m][kt] = cvt_frag(*(const float4*)s_,
                                     *(const float4*)(s_ + 4));
            }
    }

    float hreg[2][4];
    #pragma unroll
    for (int m = 0; m < 2; ++m)
        #pragma unroll
        for (int r = 0; r < 4; ++r) hreg[m][r] = 0.f;

    __syncthreads();   // buf0 h zeros visible

    for (int t = 0; t < TT; ++t) {
        _Float16* cur = lds_h + (t & 1) * HBUF;
        _Float16* nxt = lds_h + ((t & 1) ^ 1) * HBUF;
        const bool hasNext = (t + 1 < TT);

        // issue raw x(t+1) loads first (vmcnt; zero redundancy, coalesced)
        float4 pa[2][2], pb[2][2];
        if (hasNext) {
            const float* xb = x + ((size_t)(bb * TT + t + 1) * NN + n0) * HH;
            #pragma unroll
            for (int m = 0; m < 2; ++m)
                #pragma unroll
                for (int kt = 0; kt < 2; ++kt) {
                    const float* s_ = xb + (rbase + m * 16 + c0) * HH
                                    + kt * 32 + rq * 8;
                    pa[m][kt] = *(const float4*)s_;
                    pb[m][kt] = *(const float4*)(s_ + 4);
                }
        }

        // h-part A reads (4 x ds_read_b128, conflict-free)
        h8 Hf[2][2];
        #pragma unroll
        for (int m = 0; m < 2; ++m)
            #pragma unroll
            for (int kt = 0; kt < 2; ++kt)
                Hf[m][kt] = *(const h8*)(cur + (rbase + m * 16 + c0) * HK
                                         + kt * 32 + rq * 8);

        // ===== MFMA: x-part from registers first (covers ds_read latency),
        // then h-part; chain order per acc exactly R9 =====
        f32x4 a00 = {brz,  brz,  brz,  brz };
        f32x4 a01 = {bzz,  bzz,  bzz,  bzz };
        f32x4 a02 = {bin_, bin_, bin_, bin_};
        f32x4 a03 = {bhn_, bhn_, bhn_, bhn_};
        f32x4 a10 = a00, a11 = a01, a12 = a02, a13 = a03;

        __builtin_amdgcn_s_setprio(1);
        // x-part (gates r, z, gin) — register operands, no waitcnt
        a00 = MF(Xf[0][0], Bf[0], a00);  a00 = MF(Xf[0][1], Bf[1], a00);
        a10 = MF(Xf[1][0], Bf[0], a10);  a10 = MF(Xf[1][1], Bf[1], a10);
        a01 = MF(Xf[0][0], Bf[4], a01);  a01 = MF(Xf[0][1], Bf[5], a01);
        a11 = MF(Xf[1][0], Bf[4], a11);  a11 = MF(Xf[1][1], Bf[5], a11);
        a02 = MF(Xf[0][0], Bf[8], a02);  a02 = MF(Xf[0][1], Bf[9], a02);
        a12 = MF(Xf[1][0], Bf[8], a12);  a12 = MF(Xf[1][1], Bf[9], a12);
        // h-part (gates r, z, ghn)
        a00 = MF(Hf[0][0], Bf[2], a00);  a00 = MF(Hf[0][1], Bf[3], a00);
        a10 = MF(Hf[1][0], Bf[2], a10);  a10 = MF(Hf[1][1], Bf[3], a10);
        a01 = MF(Hf[0][0], Bf[6], a01);  a01 = MF(Hf[0][1], Bf[7], a01);
        a11 = MF(Hf[1][0], Bf[6], a11);  a11 = MF(Hf[1][1], Bf[7], a11);
        a03 = MF(Hf[0][0], Bf[10], a03); a03 = MF(Hf[0][1], Bf[11], a03);
        a13 = MF(Hf[1][0], Bf[10], a13); a13 = MF(Hf[1][1], Bf[11], a13);
        __builtin_amdgcn_s_setprio(0);

        // ===== epilogue: register-local gates; h -> nxt buffer =====
        #pragma unroll
        for (int r = 0; r < 4; ++r) {
            const int row0 = rbase + rq * 4 + r;
            float rg0 = sigm(a00[r]);
            float zg0 = sigm(a01[r]);
            float ng0 = tanh_f(fmaf(rg0, a03[r], a02[r]));
            float hn0 = fmaf(zg0, hreg[0][r] - ng0, ng0);   // (1-z)n + z h
            hreg[0][r] = hn0;
            float rg1 = sigm(a10[r]);
            float zg1 = sigm(a11[r]);
            float ng1 = tanh_f(fmaf(rg1, a13[r], a12[r]));
            float hn1 = fmaf(zg1, hreg[1][r] - ng1, ng1);
            hreg[1][r] = hn1;
            if (hasNext) {
                nxt[row0 * HK + j]        = (_Float16)hn0;  // ds_write_b16
                nxt[(row0 + 16) * HK + j] = (_Float16)hn1;
            }
        }

        if (hasNext) {
            // convert x(t+1) (loads issued a full phase ago; vmcnt drained)
            #pragma unroll
            for (int m = 0; m < 2; ++m)
                #pragma unroll
                for (int kt = 0; kt < 2; ++kt)
                    Xf[m][kt] = cvt_frag(pa[m][kt], pb[m][kt]);
            __syncthreads();   // nxt h ready for step t+1
        }
    }

    #pragma unroll
    for (int m = 0; m < 2; ++m)
        #pragma unroll
        for (int r = 0; r < 4; ++r)
            out[(size_t)(grow0 + rbase + m * 16 + rq * 4 + r) * HH + j] =
                hreg[m][r];
}

extern "C" void kernel_launch(void* const* d_in, const int* in_sizes, int n_in,
                              void* d_out, int out_size, void* d_ws, size_t ws_size,
                              hipStream_t stream) {
    const float* x   = (const float*)d_in[0];
    const float* Wih = (const float*)d_in[1];
    const float* Whh = (const float*)d_in[2];
    const float* bih = (const float*)d_in[3];
    const float* bhh = (const float*)d_in[4];
    float* out = (float*)d_out;

    const int lds_bytes = 2 * HBUF * (int)sizeof(_Float16);   // 18,432 B
    (void)hipFuncSetAttribute((const void*)ngru_mfma14,
                        hipFuncAttributeMaxDynamicSharedMemorySize, lds_bytes);

    dim3 grid(16384 / RPB);     // 256 blocks, 1 per CU
    dim3 block(NTHREADS);
    ngru_mfma14<<<grid, block, lds_bytes, stream>>>(x, Wih, Whh, bih, bhh, out);
}

// Round 15
// 68.719 us; speedup vs baseline: 1.7982x; 1.7982x over previous
//
#include <hip/hip_runtime.h>
#include <math.h>

// NGRU via MFMA, R15 = R9 (champion, 67.9us) + co-resident-block phase
// stagger. Only layer 1 of the 2 parallel GRU layers contributes (reference
// returns h_final[-1]); layer 0 is skipped.
//
// Shapes: x (64,48,256,64) f32; Wih/Whh (2,192,64); bih/bhh (2,192).
// rows = B*N = 16384 independent GRU sequences, T=48, H=64.
//
// R12 measured: all waves on a CU phase-locked -> LDS, MFMA, VALU/TRANS
// phases run SEQUENTIALLY (step = sum of phases = ~3400 cyc). R9's two
// co-resident blocks are independent barrier domains but launch together
// with identical step durations -> locked for all 48 steps.
// R15: blocks in the second dispatch round (blockIdx >> 8 & 1; dispatch is
// XCD round-robin i%8, 256 blocks/round, co-resident pair = {i, i+256})
// sleep ~1550 cyc once after init -> the pair runs half a step out of
// phase; each block's MFMA/epilogue overlaps the other's LDS/barrier
// phase on the shared pipes. Pure delay: numerics bit-identical to R9.
//
// Structure (R9): 512 blocks x 256 threads (4 waves), 32 rows/block,
// 2 blocks/CU. Wave nw owns cols [16nw,16nw+16) for ALL FOUR gates ->
// register-local epilogue. fp16 single-product MFMA (R9-verified).
// A = [x_t | h_{t-1}] fp16 [32][AK=136], ping-ponged -> ONE barrier/step.
// waves_per_eu(2,2): full VGPR budget at the grid-fixed residency.

#define TT 48
#define HH 64
#define GG 192
#define NN 256
#define RPB 32          // rows per block
#define NTHREADS 256    // 4 waves
#define AK 136          // A row stride in halfs (128 + 8 pad; 16B-aligned rows)
#define HBUF (RPB*AK)   // halfs per A buffer (4352)

typedef _Float16 h8 __attribute__((ext_vector_type(8)));   // 8 fp16 (4 VGPRs)
typedef __attribute__((ext_vector_type(4))) float f32x4;   // MFMA accum
typedef __attribute__((ext_vector_type(4))) unsigned u32x4;

__device__ __forceinline__ float sigm(float v) {
    return __builtin_amdgcn_rcpf(1.f + __expf(-v));
}
__device__ __forceinline__ float tanh_f(float v) {
    float a = fabsf(v);
    float e = __expf(2.f * a);
    float t = 1.f - 2.f * __builtin_amdgcn_rcpf(e + 1.f);
    return v < 0.f ? -t : t;
}
// pack 2 f32 -> dword of 2 fp16 (RNE)
__device__ __forceinline__ unsigned pkh2(float a, float b) {
    union { _Float16 h[2]; unsigned u; } c;
    c.h[0] = (_Float16)a; c.h[1] = (_Float16)b;
    return c.u;
}

#define MF(A, B, C) __builtin_amdgcn_mfma_f32_16x16x32_f16(A, B, C, 0, 0, 0)

__global__ __launch_bounds__(NTHREADS)
__attribute__((amdgpu_waves_per_eu(2, 2)))
void ngru_mfma15(const float* __restrict__ x,
                 const float* __restrict__ Wih,
                 const float* __restrict__ Whh,
                 const float* __restrict__ bih,
                 const float* __restrict__ bhh,
                 float* __restrict__ out)
{
    extern __shared__ __align__(16) _Float16 lds_h[];  // 2 x HBUF halfs

    const int tid  = threadIdx.x;
    const int lane = tid & 63;
    const int nw   = tid >> 6;          // wave 0..3 -> j slice [16nw,16nw+16)
    const int c0   = lane & 15;         // C col within tile / A row index
    const int rq   = lane >> 4;         // quarter-wave
    const int j    = nw * 16 + c0;

    const int grow0 = blockIdx.x * RPB;
    const int bb    = grow0 / NN;
    const int n0    = grow0 % NN;

    const float* Wi = Wih + GG * HH;    // layer 1
    const float* Wh = Whh + GG * HH;

    // ---- B fragments in registers: 12 kt-slots (zero tiles skipped) ----
    // slot: r -> 0..3 (kt0,1 = Wi; kt2,3 = Wh); z -> 4..7 (same);
    //       gin -> 8,9 (Wi, A kt0,1); ghn -> 10,11 (Wh, A kt2,3).
    h8 Bf[12];
    #pragma unroll
    for (int g = 0; g < 4; ++g) {
        const int ktlo = (g == 3) ? 2 : 0;
        const int kthi = (g == 2) ? 2 : 4;
        #pragma unroll
        for (int kt = ktlo; kt < kthi; ++kt) {
            const int slot = (g < 2) ? g * 4 + kt : 8 + (g - 2) * 2 + (kt & 1);
            const bool isWi = (kt < 2);
            const int gbase = (g >= 2) ? 2 : g;
            const float* src = (isWi ? Wi : Wh)
                             + (gbase * 64 + j) * HH + (kt & 1) * 32 + rq * 8;
            h8 f;
            #pragma unroll
            for (int q = 0; q < 8; ++q) f[q] = (_Float16)src[q];
            Bf[slot] = f;
        }
    }

    // ---- biases (layer 1), r/z pre-summed; n biases stay separate ----
    const float brz  = bih[GG + j]      + bhh[GG + j];
    const float bzz  = bih[GG + 64 + j] + bhh[GG + 64 + j];
    const float bin_ = bih[GG + 128 + j];
    const float bhn_ = bhh[GG + 128 + j];

    // ---- init buf0: zero h region, stage x_0 ----
    const int xrow = tid >> 3;          // 0..31
    const int xkc  = (tid & 7) * 8;     // half offset 0,8,...,56
    {
        *(u32x4*)(lds_h + xrow * AK + 64 + xkc) = (u32x4){0u, 0u, 0u, 0u};

        const float* xsrc = x + ((size_t)(bb * TT) * NN + n0 + xrow) * HH + xkc;
        float4 p0 = *(const float4*)xsrc;
        float4 p1 = *(const float4*)(xsrc + 4);
        u32x4 w = {pkh2(p0.x, p0.y), pkh2(p0.z, p0.w),
                   pkh2(p1.x, p1.y), pkh2(p1.z, p1.w)};
        *(u32x4*)(lds_h + xrow * AK + xkc) = w;
    }

    float hreg[2][4];
    #pragma unroll
    for (int m = 0; m < 2; ++m)
        #pragma unroll
        for (int r = 0; r < 4; ++r) hreg[m][r] = 0.f;

    __syncthreads();   // buf0 ready for t=0

    // ---- phase stagger: second dispatch round sleeps ~half a step so the
    // two co-resident blocks run anti-phased on the shared CU pipes ----
    if ((blockIdx.x >> 8) & 1) {
        #pragma unroll
        for (int d = 0; d < 6; ++d)
            __builtin_amdgcn_s_sleep(4);   // 6 x ~256 cyc ~= 1550 cyc
    }

    for (int t = 0; t < TT; ++t) {
        _Float16* cur = lds_h + (t & 1) * HBUF;
        _Float16* nxt = lds_h + ((t & 1) ^ 1) * HBUF;
        const bool hasNext = (t + 1 < TT);

        // prefetch x_{t+1} (HBM/L3 latency hides under the MFMA phase)
        float4 p0, p1;
        if (hasNext) {
            const float* xsrc =
                x + ((size_t)(bb * TT + t + 1) * NN + n0 + xrow) * HH + xkc;
            p0 = *(const float4*)xsrc;
            p1 = *(const float4*)(xsrc + 4);
        }

        // acc preloaded with biases (constant across the 4 C-regs of a tile)
        f32x4 acc[2][4];
        #pragma unroll
        for (int m = 0; m < 2; ++m) {
            acc[m][0] = (f32x4){brz,  brz,  brz,  brz };
            acc[m][1] = (f32x4){bzz,  bzz,  bzz,  bzz };
            acc[m][2] = (f32x4){bin_, bin_, bin_, bin_};
            acc[m][3] = (f32x4){bhn_, bhn_, bhn_, bhn_};
        }

        // ===== MFMA: 4 gate-tiles x 2 m-tiles, single fp16 product =====
        __builtin_amdgcn_s_setprio(1);
        #pragma unroll
        for (int m = 0; m < 2; ++m) {
            const _Float16* ab = cur + (m * 16 + c0) * AK + rq * 8;
            h8 A_[4];
            #pragma unroll
            for (int kt = 0; kt < 4; ++kt)
                A_[kt] = *(const h8*)(ab + kt * 32);
            #pragma unroll
            for (int g = 0; g < 4; ++g) {
                #pragma unroll
                for (int kt = 0; kt < 4; ++kt) {
                    if ((g == 2 && kt >= 2) || (g == 3 && kt < 2)) continue;
                    const int slot = (g < 2) ? g * 4 + kt
                                             : 8 + (g - 2) * 2 + (kt & 1);
                    acc[m][g] = __builtin_amdgcn_mfma_f32_16x16x32_f16(
                        A_[kt], Bf[slot], acc[m][g], 0, 0, 0);
                }
            }
        }
        __builtin_amdgcn_s_setprio(0);

        // ===== epilogue: register-local gates; h -> nxt buffer =====
        #pragma unroll
        for (int m = 0; m < 2; ++m) {
            #pragma unroll
            for (int r = 0; r < 4; ++r) {
                const int row = m * 16 + rq * 4 + r;
                float rg = sigm(acc[m][0][r]);
                float zg = sigm(acc[m][1][r]);
                float ng = tanh_f(fmaf(rg, acc[m][3][r], acc[m][2][r]));
                float hn = fmaf(zg, hreg[m][r] - ng, ng);   // (1-z)n + z h
                hreg[m][r] = hn;
                if (hasNext)
                    nxt[row * AK + 64 + j] = (_Float16)hn;   // ds_write_b16
            }
        }

        if (hasNext) {
            u32x4 w = {pkh2(p0.x, p0.y), pkh2(p0.z, p0.w),
                       pkh2(p1.x, p1.y), pkh2(p1.z, p1.w)};
            *(u32x4*)(nxt + xrow * AK + xkc) = w;
            __syncthreads();   // nxt (h_t + x_{t+1}) ready for step t+1
        }
    }

    #pragma unroll
    for (int m = 0; m < 2; ++m)
        #pragma unroll
        for (int r = 0; r < 4; ++r)
            out[(size_t)(grow0 + m * 16 + rq * 4 + r) * HH + j] = hreg[m][r];
}

extern "C" void kernel_launch(void* const* d_in, const int* in_sizes, int n_in,
                              void* d_out, int out_size, void* d_ws, size_t ws_size,
                              hipStream_t stream) {
    const float* x   = (const float*)d_in[0];
    const float* Wih = (const float*)d_in[1];
    const float* Whh = (const float*)d_in[2];
    const float* bih = (const float*)d_in[3];
    const float* bhh = (const float*)d_in[4];
    float* out = (float*)d_out;

    const int lds_bytes = 2 * HBUF * (int)sizeof(_Float16);   // 17,408 B
    (void)hipFuncSetAttribute((const void*)ngru_mfma15,
                        hipFuncAttributeMaxDynamicSharedMemorySize, lds_bytes);

    dim3 grid(16384 / RPB);     // 512 blocks, 2 per CU
    dim3 block(NTHREADS);
    ngru_mfma15<<<grid, block, lds_bytes, stream>>>(x, Wih, Whh, bih, bhh, out);
}